// Round 23
// baseline (128.508 us; speedup 1.0000x reference)
//
#include <hip/hip_runtime.h>
#include <hip/hip_bf16.h>
#include <stdint.h>

// Problem: B=2, T=2048, D=1024, H=16, hd=64.  M = B*T = 4096.
// Pipeline: x->bf16 ; w^T->bf16 ; QKV gemm w/ fused bias+RoPE+head-split ;
// flash attn (KV-split 2-way, 8-wave blocks, MAX-FREE softmax) ; combine ;
// out gemm (64x128 tiles, 2 blocks/CU).
// Workspace layout (bytes), < 64 MiB (R2 post-mortem):
//   0        x_bf16 [4096][1024]      -- later reused as partialO [2][65536][64] bf16
//   8388608  wqkvT  [3072][1024]      -- (PO spans [0, 16777216))
//   16777216 Q      [32][2048][64]    (pre-scaled by log2e/8, RoPE'd)
//   25165824 K      [32][2048][64]    (RoPE'd)
//   33554432 V^T    [32][64][2048]    (transposed; key dim INTERLEAVED per
//                                      64-block: pos(16a+4g+r)=16g+8(a>>1)+4(a&1)+r)
//   41943040 attn   [4096][1024]
//   50331648 woutT  [1024][1024]
//   52428800 l      [2][65536] float
// Max-free softmax: bf16-input scores are bounded << 2^120 in log2 domain, so
// P=exp2(S) raw cannot overflow and the reference-max cancels exactly in O/l.
// R15 (x2 w/ R10): V direct-from-L2 loses to LDS-staged V.
// R18: fusing combine into out-gemm regressed.  R19: qkv 64x128 retile
// regressed.  R21: qkv BK=64 neutral.  R22: padded epilogue exchange (68
// f32/row) -- conflicts 4.85M->2.23M, attn -2us (prediction matched).
// R23: T5 s_setprio(1) around attn MFMA clusters (m191: +4-7% attn; attn only,
// NOT the gemms per m190).

typedef __bf16 bf16;
typedef __bf16 bf16x8 __attribute__((ext_vector_type(8)));
typedef __bf16 bf16x4 __attribute__((ext_vector_type(4)));
typedef float  f32x4  __attribute__((ext_vector_type(4)));

__device__ __forceinline__ void gload16(void* lds, const void* g) {
  __builtin_amdgcn_global_load_lds((__attribute__((address_space(1))) void*)(void*)g,
                                   (__attribute__((address_space(3))) void*)lds, 16, 0, 0);
}

// ---------------- conversion kernels ----------------

__global__ void k_convert_x(const float* __restrict__ x, bf16* __restrict__ xb, int n) {
  int i = (blockIdx.x * blockDim.x + threadIdx.x) * 4;
  if (i >= n) return;
  float4 v = *(const float4*)(x + i);
  bf16x4 o;
  o.x = (bf16)v.x; o.y = (bf16)v.y; o.z = (bf16)v.z; o.w = (bf16)v.w;
  *(bf16x4*)(xb + i) = o;
}

__global__ void k_transpose_bf16(const float* __restrict__ in, bf16* __restrict__ out,
                                 int rows, int cols) {
  __shared__ float t[32][33];
  int c0 = blockIdx.x * 32, r0 = blockIdx.y * 32;
  for (int i = threadIdx.y; i < 32; i += 8)
    t[i][threadIdx.x] = in[(size_t)(r0 + i) * cols + c0 + threadIdx.x];
  __syncthreads();
  for (int i = threadIdx.y; i < 32; i += 8)
    out[(size_t)(c0 + i) * rows + r0 + threadIdx.x] = (bf16)t[threadIdx.x][i];
}

// ---------------- QKV GEMM with fused bias + RoPE + head split ----------------
// RoPE trig via native v_sin/v_cos (input in revolutions, fract-reduced).

__global__ __launch_bounds__(256)
void k_gemm_qkv(const bf16* __restrict__ A, const bf16* __restrict__ Bt,
                const float* __restrict__ bias, bf16* __restrict__ Qd,
                bf16* __restrict__ Kd, bf16* __restrict__ Vtd) {
  alignas(16) __shared__ bf16 lds_a[128 * 32];
  alignas(16) __shared__ bf16 lds_b[128 * 32];
  const int tid = threadIdx.x;
  const int lane = tid & 63, w = tid >> 6;
  const int wr = w >> 1, wc = w & 1;
  const int bid = blockIdx.x;
  const int swz = (bid & 7) * 96 + (bid >> 3);
  const int br = swz / 24, bc = swz % 24;
  const int r16 = lane & 15, g4 = lane >> 4;

  f32x4 acc[4][4] = {};
  const bf16* gA = A + (size_t)(br * 128 + (lane >> 2)) * 1024 + (lane & 3) * 8;
  const bf16* gB = Bt + (size_t)(bc * 128 + (lane >> 2)) * 1024 + (lane & 3) * 8;

  for (int kt = 0; kt < 32; ++kt) {
    const int ko = kt * 32;
#pragma unroll
    for (int it = 0; it < 2; ++it) {
      const int row0 = 16 * (4 * it + w);
      gload16(&lds_a[row0 * 32], gA + (size_t)row0 * 1024 + ko);
      gload16(&lds_b[row0 * 32], gB + (size_t)row0 * 1024 + ko);
    }
    __syncthreads();
    bf16x8 af[4], bfr[4];
#pragma unroll
    for (int m = 0; m < 4; ++m)
      af[m] = *(const bf16x8*)&lds_a[(wr * 64 + 16 * m + r16) * 32 + g4 * 8];
#pragma unroll
    for (int n = 0; n < 4; ++n)
      bfr[n] = *(const bf16x8*)&lds_b[(wc * 64 + 16 * n + r16) * 32 + g4 * 8];
#pragma unroll
    for (int m = 0; m < 4; ++m)
#pragma unroll
      for (int n = 0; n < 4; ++n)
        acc[m][n] = __builtin_amdgcn_mfma_f32_16x16x32_bf16(af[m], bfr[n], acc[m][n], 0, 0, 0);
    __syncthreads();
  }

  const int reg = bc >> 3;                       // 0=Q, 1=K, 2=V
  const int h = ((bc & 7) << 1) | wc;            // head 0..15
  const float bq = 0.125f * 1.4426950408889634f; // (1/sqrt(64)) * log2(e)
  const float Lc = 13.287712379549449f / 32.0f;  // log2(10000)/32
  const float inv2pi = 0.15915494309189535f;
  const float if0r = exp2f(-(float)r16 * Lc) * inv2pi;        // rev per t
  const float if1r = exp2f(-(float)(16 + r16) * Lc) * inv2pi;
  float bv[4];
#pragma unroll
  for (int n = 0; n < 4; ++n) bv[n] = bias[bc * 128 + wc * 64 + 16 * n + r16];

  if (reg == 2) {
    // V: V^T[b*16+h][d][t'], key pos interleaved within each 64-block:
    // t = 64blk+16a+4g+r -> t' = 64blk+16g+8(a>>1)+4(a&1)+r
#pragma unroll
    for (int m = 0; m < 4; ++m) {
      const int row0 = br * 128 + wr * 64 + 16 * m + 4 * g4;
      const int t0 = row0 & 2047, b = row0 >> 11;
      const int pos = (t0 & ~63) | (((t0 >> 2) & 3) << 4) | (((t0 >> 5) & 1) << 3) |
                      (((t0 >> 4) & 1) << 2);
#pragma unroll
      for (int n = 0; n < 4; ++n) {
        bf16x4 pk;
#pragma unroll
        for (int r = 0; r < 4; ++r) pk[r] = (bf16)(acc[m][n][r] + bv[n]);
        *(bf16x4*)(Vtd + ((size_t)((b * 16 + h) * 64) + 16 * n + r16) * 2048 + pos) = pk;
      }
    }
  } else {
    bf16* dst = (reg == 0) ? Qd : Kd;
#pragma unroll
    for (int m = 0; m < 4; ++m) {
#pragma unroll
      for (int r = 0; r < 4; ++r) {
        const int row = br * 128 + wr * 64 + 16 * m + 4 * g4 + r;
        const int t = row & 2047, b = row >> 11;
        bf16* o = dst + ((size_t)(b * 16 + h) * 2048 + t) * 64;
        const float v0 = acc[m][0][r] + bv[0];
        const float v1 = acc[m][1][r] + bv[1];
        const float v2 = acc[m][2][r] + bv[2];
        const float v3 = acc[m][3][r] + bv[3];
        const float tf = (float)t;
        float rv0 = tf * if0r; rv0 -= floorf(rv0);
        float rv1 = tf * if1r; rv1 -= floorf(rv1);
        const float s0 = __builtin_amdgcn_sinf(rv0), c0 = __builtin_amdgcn_cosf(rv0);
        const float s1 = __builtin_amdgcn_sinf(rv1), c1 = __builtin_amdgcn_cosf(rv1);
        float r0 = v0 * c0 - v2 * s0, r2 = v0 * s0 + v2 * c0;
        float r1 = v1 * c1 - v3 * s1, r3 = v1 * s1 + v3 * c1;
        if (reg == 0) { r0 *= bq; r1 *= bq; r2 *= bq; r3 *= bq; }
        o[r16]      = (bf16)r0;
        o[16 + r16] = (bf16)r1;
        o[32 + r16] = (bf16)r2;
        o[48 + r16] = (bf16)r3;
      }
    }
  }
}

// ---------------- out GEMM (64x128 tiles, grid 512 = 2 blocks/CU) ----------------
// Wave w owns the 64x32 column strip cols [32w, 32w+32).

__global__ __launch_bounds__(256)
void k_gemm_out(const bf16* __restrict__ A, const bf16* __restrict__ Bt,
                const float* __restrict__ bias, float* __restrict__ Cp,
                int M, int N, int K) {
  alignas(16) __shared__ bf16 lds_a[64 * 32];
  alignas(16) __shared__ bf16 lds_b[128 * 32];
  const int tid = threadIdx.x;
  const int lane = tid & 63, w = tid >> 6;
  const int nb = N >> 7;
  const int nwg = gridDim.x;
  const int bid = blockIdx.x;
  const int swz = (bid & 7) * (nwg >> 3) + (bid >> 3);
  const int br = swz / nb, bc = swz % nb;
  const int r16 = lane & 15, g4 = lane >> 4;

  f32x4 acc[4][2] = {};
  const int nk = K >> 5;
  const bf16* gA = A + (size_t)(br * 64 + 16 * w + (lane >> 2)) * K + (lane & 3) * 8;
  const bf16* gB = Bt + (size_t)(bc * 128 + (lane >> 2)) * K + (lane & 3) * 8;

  for (int kt = 0; kt < nk; ++kt) {
    const int ko = kt * 32;
    gload16(&lds_a[w * 512], gA + ko);
#pragma unroll
    for (int c = 0; c < 2; ++c) {
      const int row0 = 16 * (2 * w + c);
      gload16(&lds_b[row0 * 32], gB + (size_t)row0 * K + ko);
    }
    __syncthreads();
    bf16x8 af[4], bfr[2];
#pragma unroll
    for (int m = 0; m < 4; ++m)
      af[m] = *(const bf16x8*)&lds_a[(16 * m + r16) * 32 + g4 * 8];
#pragma unroll
    for (int n = 0; n < 2; ++n)
      bfr[n] = *(const bf16x8*)&lds_b[(32 * w + 16 * n + r16) * 32 + g4 * 8];
#pragma unroll
    for (int m = 0; m < 4; ++m)
#pragma unroll
      for (int n = 0; n < 2; ++n)
        acc[m][n] = __builtin_amdgcn_mfma_f32_16x16x32_bf16(af[m], bfr[n], acc[m][n], 0, 0, 0);
    __syncthreads();
  }

#pragma unroll
  for (int m = 0; m < 4; ++m) {
    const int row = br * 64 + 16 * m + 4 * g4;
#pragma unroll
    for (int n = 0; n < 2; ++n) {
      const int col = bc * 128 + 32 * w + 16 * n + r16;
      const float bvv = bias[col];
#pragma unroll
      for (int r = 0; r < 4; ++r)
        Cp[(size_t)(row + r) * N + col] = acc[m][n][r] + bvv;
    }
  }
}

// ---------------- flash attention (KV-split 2-way, 8-wave blocks) --------------
// 1D grid 1024 (XCD-swizzled), 512 threads (8 waves).  Block = 128 q-rows x one
// key-half (16 of 32 tiles).  Wave (qh,kh): qh=w>>1 (32 q-rows), kh=w&1 (32
// keys/tile).  K + interleaved-V^T staged via gload_lds (dbuf 2x16KB) -- ONE
// staged tile feeds 8 waves.  Max-free softmax; l via ones-row mfma.
// Epilogue exchange padded to 68 f32/row (2-way banks).  T5: setprio(1)
// around the MFMA clusters (QK and PV).

__global__ __launch_bounds__(512)
void k_attn(const bf16* __restrict__ Qg, const bf16* __restrict__ Kg,
            const bf16* __restrict__ Vtg, bf16* __restrict__ PO,
            float* __restrict__ lsum) {
  alignas(16) __shared__ char smem[35328];   // staging 32KB; epilogue 128*68*4+512
  bf16* kbufs = (bf16*)smem;                 // [2][4096]
  bf16* vbufs = (bf16*)(smem + 16384);       // [2][4096]
  const int tid = threadIdx.x, lane = tid & 63, w = tid >> 6;   // w 0..7
  const int bid = blockIdx.x;
  const int swz = (bid & 7) * 128 + (bid >> 3);
  const int half = swz & 1;
  const int id2 = swz >> 1;                       // 0..511
  const int bh = id2 >> 4, q0 = (id2 & 15) * 128;
  const int qh = w >> 1, kh = w & 1;
  const int r16 = lane & 15, g4 = lane >> 4;
  const char* Kb  = (const char*)(Kg  + (size_t)bh * 2048 * 64);
  const char* Vtb = (const char*)(Vtg + (size_t)bh * 64 * 2048);
  const bf16* Qb  = Qg + (size_t)bh * 2048 * 64;

  const int rl = lane >> 3;
  const int colx = ((lane & 7) * 16) ^ (rl << 4);

  bf16x8 qf[2][2];
#pragma unroll
  for (int g = 0; g < 2; ++g) {
    const int qrow = q0 + 32 * qh + 16 * g + r16;
    qf[g][0] = *(const bf16x8*)(Qb + (size_t)qrow * 64 + g4 * 8);
    qf[g][1] = *(const bf16x8*)(Qb + (size_t)qrow * 64 + 32 + g4 * 8);
  }

  f32x4 O[2][4] = {};
  f32x4 O4[2] = {};
  bf16x8 ones8 = {};
  if (r16 == 0)
#pragma unroll
    for (int j = 0; j < 8; ++j) ones8[j] = (bf16)1.f;

  // 8 waves: wave w stages rows 8w..8w+7 (1KB) of each tile
#define STAGE(bufi, t0)                                                          \
  {                                                                              \
    const int row = 8 * w + rl;                                                  \
    gload16(&kbufs[(bufi) * 4096 + w * 512],                                     \
            Kb + (size_t)((t0) + row) * 128 + colx);                             \
    gload16(&vbufs[(bufi) * 4096 + w * 512],                                     \
            Vtb + (size_t)row * 4096 + (size_t)(t0) * 2 + colx);                 \
  }

  const int it0 = half * 16;
  STAGE(0, it0 * 64);
  __syncthreads();

  const int rsw = (r16 & 7) << 4;

#pragma unroll 1
  for (int ii = 0; ii < 16; ++ii) {
    const int bsel = ii & 1;
    if (ii + 1 < 16) STAGE(bsel ^ 1, (it0 + ii + 1) * 64);
    const char* kb = (const char*)kbufs + bsel * 8192 + r16 * 128;
    const char* vb = (const char*)vbufs + bsel * 8192 + r16 * 128;

    // this wave's keys: n = 2*kh + nl, nl = 0,1 (32 keys)
    f32x4 S[2][2];
    __builtin_amdgcn_s_setprio(1);
#pragma unroll
    for (int nl = 0; nl < 2; ++nl) {
      const int n = 2 * kh + nl;
      bf16x8 kf0 = *(const bf16x8*)(kb + n * 2048 + ((g4 * 16) ^ rsw));
      bf16x8 kf1 = *(const bf16x8*)(kb + n * 2048 + ((64 + g4 * 16) ^ rsw));
      f32x4 s = {};
      s = __builtin_amdgcn_mfma_f32_16x16x32_bf16(kf0, qf[0][0], s, 0, 0, 0);
      s = __builtin_amdgcn_mfma_f32_16x16x32_bf16(kf1, qf[0][1], s, 0, 0, 0);
      S[0][nl] = s;
      f32x4 t = {};
      t = __builtin_amdgcn_mfma_f32_16x16x32_bf16(kf0, qf[1][0], t, 0, 0, 0);
      t = __builtin_amdgcn_mfma_f32_16x16x32_bf16(kf1, qf[1][1], t, 0, 0, 0);
      S[1][nl] = t;
    }
    __builtin_amdgcn_s_setprio(0);

    // max-free: P = exp2(S) raw, packed as one K=32 B-fragment per q-group
    bf16x8 pb[2];
#pragma unroll
    for (int g = 0; g < 2; ++g)
#pragma unroll
      for (int nl = 0; nl < 2; ++nl)
#pragma unroll
        for (int r = 0; r < 4; ++r)
          pb[g][nl * 4 + r] = (bf16)exp2f(S[g][nl][r]);

    // O += V^T P^T over this wave's 32 keys (A-frag = interleaved-V b128)
    __builtin_amdgcn_s_setprio(1);
#pragma unroll
    for (int dn = 0; dn < 4; ++dn) {
      bf16x8 vf = *(const bf16x8*)(vb + dn * 2048 + ((32 * g4 + 16 * kh) ^ rsw));
      O[0][dn] = __builtin_amdgcn_mfma_f32_16x16x32_bf16(vf, pb[0], O[0][dn], 0, 0, 0);
      O[1][dn] = __builtin_amdgcn_mfma_f32_16x16x32_bf16(vf, pb[1], O[1][dn], 0, 0, 0);
    }
    O4[0] = __builtin_amdgcn_mfma_f32_16x16x32_bf16(ones8, pb[0], O4[0], 0, 0, 0);
    O4[1] = __builtin_amdgcn_mfma_f32_16x16x32_bf16(ones8, pb[1], O4[1], 0, 0, 0);
    __builtin_amdgcn_s_setprio(0);
    __syncthreads();
  }
#undef STAGE

  // cross-wave kh-combine (plain sums, max-free) via LDS, then store partials.
  // obuf padded to 68 f32/row: r16-lane stride 272B -> 2-way banks (free).
  float* obuf = (float*)smem;                 // [128][68] f32 = 34816 B
  float* lbuf = (float*)(smem + 34816);       // [128]
  if (kh == 1) {
#pragma unroll
    for (int g = 0; g < 2; ++g) {
#pragma unroll
      for (int dn = 0; dn < 4; ++dn)
        *(f32x4*)&obuf[(qh * 32 + g * 16 + r16) * 68 + 16 * dn + 4 * g4] = O[g][dn];
      if (g4 == 0) lbuf[qh * 32 + g * 16 + r16] = O4[g][0];
    }
  }
  __syncthreads();
  if (kh == 0) {
    bf16* POh = PO + (size_t)half * 4194304;
#pragma unroll
    for (int g = 0; g < 2; ++g) {
      const int row = bh * 2048 + q0 + 32 * qh + 16 * g + r16;
      const float ls = __shfl(O4[g][0], r16, 64) + lbuf[qh * 32 + g * 16 + r16];
#pragma unroll
      for (int dn = 0; dn < 4; ++dn) {
        f32x4 os = O[g][dn];
        f32x4 ot = *(const f32x4*)&obuf[(qh * 32 + g * 16 + r16) * 68 + 16 * dn + 4 * g4];
        bf16x4 ov;
#pragma unroll
        for (int r = 0; r < 4; ++r) ov[r] = (bf16)(os[r] + ot[r]);
        *(bf16x4*)(POh + (size_t)row * 64 + 16 * dn + 4 * g4) = ov;
      }
      if (g4 == 0) lsum[half * 65536 + row] = ls;
    }
  }
}

// ---------------- combine: O = (O0 + O1) / (l0 + l1) ----------------

__global__ __launch_bounds__(256)
void k_combine(const bf16* __restrict__ PO, const float* __restrict__ lsum,
               bf16* __restrict__ attnb) {
  const int idx = blockIdx.x * 256 + threadIdx.x;   // 524288 = 65536 rows x 8 segs
  const int row = idx >> 3, seg = idx & 7;
  const float inv = 1.f / (lsum[row] + lsum[65536 + row]);
  bf16x8 p0 = *(const bf16x8*)(PO + (size_t)row * 64 + seg * 8);
  bf16x8 p1 = *(const bf16x8*)(PO + 4194304 + (size_t)row * 64 + seg * 8);
  bf16x8 o;
#pragma unroll
  for (int j = 0; j < 8; ++j)
    o[j] = (bf16)(((float)p0[j] + (float)p1[j]) * inv);
  const int bh = row >> 11, t = row & 2047;
  const int b = bh >> 4, h = bh & 15;
  *(bf16x8*)(attnb + ((size_t)(b * 2048 + t)) * 1024 + h * 64 + seg * 8) = o;
}

// ---------------- launch ----------------

extern "C" void kernel_launch(void* const* d_in, const int* in_sizes, int n_in,
                              void* d_out, int out_size, void* d_ws, size_t ws_size,
                              hipStream_t stream) {
  const float* x     = (const float*)d_in[0];
  const float* w_qkv = (const float*)d_in[1];
  const float* b_qkv = (const float*)d_in[2];
  const float* w_out = (const float*)d_in[3];
  const float* b_out = (const float*)d_in[4];
  float* out = (float*)d_out;

  char* ws = (char*)d_ws;
  bf16* xb    = (bf16*)(ws);                 // reused as PO after qkv
  bf16* wqkvT = (bf16*)(ws + 8388608);
  bf16* Qb    = (bf16*)(ws + 16777216);
  bf16* Kb    = (bf16*)(ws + 25165824);
  bf16* Vtb   = (bf16*)(ws + 33554432);
  bf16* attnb = (bf16*)(ws + 41943040);
  bf16* woutT = (bf16*)(ws + 50331648);
  float* lsum = (float*)(ws + 52428800);
  bf16* PO    = (bf16*)(ws);                 // [2][65536][64] over xb+wqkvT

  k_convert_x<<<4096 * 1024 / 4 / 256, 256, 0, stream>>>(x, xb, 4096 * 1024);
  k_transpose_bf16<<<dim3(3072 / 32, 1024 / 32), dim3(32, 8), 0, stream>>>(w_qkv, wqkvT, 1024, 3072);
  k_transpose_bf16<<<dim3(1024 / 32, 1024 / 32), dim3(32, 8), 0, stream>>>(w_out, woutT, 1024, 1024);
  k_gemm_qkv<<<32 * 24, 256, 0, stream>>>(xb, wqkvT, b_qkv, Qb, Kb, Vtb);
  k_attn<<<1024, 512, 0, stream>>>(Qb, Kb, Vtb, PO, lsum);
  k_combine<<<2048, 256, 0, stream>>>(PO, lsum, attnb);
  k_gemm_out<<<512, 256, 0, stream>>>(attnb, woutT, b_out, out, 4096, 1024, 1024);
}

// Round 24
// 128.133 us; speedup vs baseline: 1.0029x; 1.0029x over previous
//
#include <hip/hip_runtime.h>
#include <hip/hip_bf16.h>
#include <stdint.h>

// Problem: B=2, T=2048, D=1024, H=16, hd=64.  M = B*T = 4096.
// Pipeline: x->bf16 ; w^T->bf16 ; QKV gemm w/ fused bias+RoPE+head-split ;
// flash attn (KV-split 2-way, 8-wave blocks, MAX-FREE softmax) ; combine ;
// out gemm (64x128 tiles, 2 blocks/CU).
// Workspace layout (bytes), < 64 MiB (R2 post-mortem):
//   0        x_bf16 [4096][1024]      -- later reused as partialO [2][65536][64] bf16
//   8388608  wqkvT  [3072][1024]      -- (PO spans [0, 16777216))
//   16777216 Q      [32][2048][64]    (pre-scaled by log2e/8, RoPE'd)
//   25165824 K      [32][2048][64]    (RoPE'd)
//   33554432 V^T    [32][64][2048]    (transposed; key dim INTERLEAVED per
//                                      64-block: pos(16a+4g+r)=16g+8(a>>1)+4(a&1)+r)
//   41943040 attn   [4096][1024]
//   50331648 woutT  [1024][1024]
//   52428800 l      [2][65536] float
// Max-free softmax: bf16-input scores are bounded << 2^120 in log2 domain, so
// P=exp2(S) raw cannot overflow and the reference-max cancels exactly in O/l.
// R15 (x2 w/ R10): V direct-from-L2 loses to LDS-staged V.
// R18: fusing combine into out-gemm regressed.  R19: qkv 64x128 retile
// regressed.  R21: qkv BK=64 neutral.  R22: padded epilogue exchange (68
// f32/row) -- conflicts 4.85M->2.23M, attn -2us (prediction matched).
// R23: T5 s_setprio(1) around attn MFMA clusters (m191: +4-7% attn; attn only,
// NOT the gemms per m190).

typedef __bf16 bf16;
typedef __bf16 bf16x8 __attribute__((ext_vector_type(8)));
typedef __bf16 bf16x4 __attribute__((ext_vector_type(4)));
typedef float  f32x4  __attribute__((ext_vector_type(4)));

__device__ __forceinline__ void gload16(void* lds, const void* g) {
  __builtin_amdgcn_global_load_lds((__attribute__((address_space(1))) void*)(void*)g,
                                   (__attribute__((address_space(3))) void*)lds, 16, 0, 0);
}

// ---------------- conversion kernels ----------------

__global__ void k_convert_x(const float* __restrict__ x, bf16* __restrict__ xb, int n) {
  int i = (blockIdx.x * blockDim.x + threadIdx.x) * 4;
  if (i >= n) return;
  float4 v = *(const float4*)(x + i);
  bf16x4 o;
  o.x = (bf16)v.x; o.y = (bf16)v.y; o.z = (bf16)v.z; o.w = (bf16)v.w;
  *(bf16x4*)(xb + i) = o;
}

__global__ void k_transpose_bf16(const float* __restrict__ in, bf16* __restrict__ out,
                                 int rows, int cols) {
  __shared__ float t[32][33];
  int c0 = blockIdx.x * 32, r0 = blockIdx.y * 32;
  for (int i = threadIdx.y; i < 32; i += 8)
    t[i][threadIdx.x] = in[(size_t)(r0 + i) * cols + c0 + threadIdx.x];
  __syncthreads();
  for (int i = threadIdx.y; i < 32; i += 8)
    out[(size_t)(c0 + i) * rows + r0 + threadIdx.x] = (bf16)t[threadIdx.x][i];
}

// ---------------- QKV GEMM with fused bias + RoPE + head split ----------------
// RoPE trig via native v_sin/v_cos (input in revolutions, fract-reduced).

__global__ __launch_bounds__(256)
void k_gemm_qkv(const bf16* __restrict__ A, const bf16* __restrict__ Bt,
                const float* __restrict__ bias, bf16* __restrict__ Qd,
                bf16* __restrict__ Kd, bf16* __restrict__ Vtd) {
  alignas(16) __shared__ bf16 lds_a[128 * 32];
  alignas(16) __shared__ bf16 lds_b[128 * 32];
  const int tid = threadIdx.x;
  const int lane = tid & 63, w = tid >> 6;
  const int wr = w >> 1, wc = w & 1;
  const int bid = blockIdx.x;
  const int swz = (bid & 7) * 96 + (bid >> 3);
  const int br = swz / 24, bc = swz % 24;
  const int r16 = lane & 15, g4 = lane >> 4;

  f32x4 acc[4][4] = {};
  const bf16* gA = A + (size_t)(br * 128 + (lane >> 2)) * 1024 + (lane & 3) * 8;
  const bf16* gB = Bt + (size_t)(bc * 128 + (lane >> 2)) * 1024 + (lane & 3) * 8;

  for (int kt = 0; kt < 32; ++kt) {
    const int ko = kt * 32;
#pragma unroll
    for (int it = 0; it < 2; ++it) {
      const int row0 = 16 * (4 * it + w);
      gload16(&lds_a[row0 * 32], gA + (size_t)row0 * 1024 + ko);
      gload16(&lds_b[row0 * 32], gB + (size_t)row0 * 1024 + ko);
    }
    __syncthreads();
    bf16x8 af[4], bfr[4];
#pragma unroll
    for (int m = 0; m < 4; ++m)
      af[m] = *(const bf16x8*)&lds_a[(wr * 64 + 16 * m + r16) * 32 + g4 * 8];
#pragma unroll
    for (int n = 0; n < 4; ++n)
      bfr[n] = *(const bf16x8*)&lds_b[(wc * 64 + 16 * n + r16) * 32 + g4 * 8];
#pragma unroll
    for (int m = 0; m < 4; ++m)
#pragma unroll
      for (int n = 0; n < 4; ++n)
        acc[m][n] = __builtin_amdgcn_mfma_f32_16x16x32_bf16(af[m], bfr[n], acc[m][n], 0, 0, 0);
    __syncthreads();
  }

  const int reg = bc >> 3;                       // 0=Q, 1=K, 2=V
  const int h = ((bc & 7) << 1) | wc;            // head 0..15
  const float bq = 0.125f * 1.4426950408889634f; // (1/sqrt(64)) * log2(e)
  const float Lc = 13.287712379549449f / 32.0f;  // log2(10000)/32
  const float inv2pi = 0.15915494309189535f;
  const float if0r = exp2f(-(float)r16 * Lc) * inv2pi;        // rev per t
  const float if1r = exp2f(-(float)(16 + r16) * Lc) * inv2pi;
  float bv[4];
#pragma unroll
  for (int n = 0; n < 4; ++n) bv[n] = bias[bc * 128 + wc * 64 + 16 * n + r16];

  if (reg == 2) {
    // V: V^T[b*16+h][d][t'], key pos interleaved within each 64-block:
    // t = 64blk+16a+4g+r -> t' = 64blk+16g+8(a>>1)+4(a&1)+r
#pragma unroll
    for (int m = 0; m < 4; ++m) {
      const int row0 = br * 128 + wr * 64 + 16 * m + 4 * g4;
      const int t0 = row0 & 2047, b = row0 >> 11;
      const int pos = (t0 & ~63) | (((t0 >> 2) & 3) << 4) | (((t0 >> 5) & 1) << 3) |
                      (((t0 >> 4) & 1) << 2);
#pragma unroll
      for (int n = 0; n < 4; ++n) {
        bf16x4 pk;
#pragma unroll
        for (int r = 0; r < 4; ++r) pk[r] = (bf16)(acc[m][n][r] + bv[n]);
        *(bf16x4*)(Vtd + ((size_t)((b * 16 + h) * 64) + 16 * n + r16) * 2048 + pos) = pk;
      }
    }
  } else {
    bf16* dst = (reg == 0) ? Qd : Kd;
#pragma unroll
    for (int m = 0; m < 4; ++m) {
#pragma unroll
      for (int r = 0; r < 4; ++r) {
        const int row = br * 128 + wr * 64 + 16 * m + 4 * g4 + r;
        const int t = row & 2047, b = row >> 11;
        bf16* o = dst + ((size_t)(b * 16 + h) * 2048 + t) * 64;
        const float v0 = acc[m][0][r] + bv[0];
        const float v1 = acc[m][1][r] + bv[1];
        const float v2 = acc[m][2][r] + bv[2];
        const float v3 = acc[m][3][r] + bv[3];
        const float tf = (float)t;
        float rv0 = tf * if0r; rv0 -= floorf(rv0);
        float rv1 = tf * if1r; rv1 -= floorf(rv1);
        const float s0 = __builtin_amdgcn_sinf(rv0), c0 = __builtin_amdgcn_cosf(rv0);
        const float s1 = __builtin_amdgcn_sinf(rv1), c1 = __builtin_amdgcn_cosf(rv1);
        float r0 = v0 * c0 - v2 * s0, r2 = v0 * s0 + v2 * c0;
        float r1 = v1 * c1 - v3 * s1, r3 = v1 * s1 + v3 * c1;
        if (reg == 0) { r0 *= bq; r1 *= bq; r2 *= bq; r3 *= bq; }
        o[r16]      = (bf16)r0;
        o[16 + r16] = (bf16)r1;
        o[32 + r16] = (bf16)r2;
        o[48 + r16] = (bf16)r3;
      }
    }
  }
}

// ---------------- out GEMM (64x128 tiles, grid 512 = 2 blocks/CU) ----------------
// Wave w owns the 64x32 column strip cols [32w, 32w+32).

__global__ __launch_bounds__(256)
void k_gemm_out(const bf16* __restrict__ A, const bf16* __restrict__ Bt,
                const float* __restrict__ bias, float* __restrict__ Cp,
                int M, int N, int K) {
  alignas(16) __shared__ bf16 lds_a[64 * 32];
  alignas(16) __shared__ bf16 lds_b[128 * 32];
  const int tid = threadIdx.x;
  const int lane = tid & 63, w = tid >> 6;
  const int nb = N >> 7;
  const int nwg = gridDim.x;
  const int bid = blockIdx.x;
  const int swz = (bid & 7) * (nwg >> 3) + (bid >> 3);
  const int br = swz / nb, bc = swz % nb;
  const int r16 = lane & 15, g4 = lane >> 4;

  f32x4 acc[4][2] = {};
  const int nk = K >> 5;
  const bf16* gA = A + (size_t)(br * 64 + 16 * w + (lane >> 2)) * K + (lane & 3) * 8;
  const bf16* gB = Bt + (size_t)(bc * 128 + (lane >> 2)) * K + (lane & 3) * 8;

  for (int kt = 0; kt < nk; ++kt) {
    const int ko = kt * 32;
    gload16(&lds_a[w * 512], gA + ko);
#pragma unroll
    for (int c = 0; c < 2; ++c) {
      const int row0 = 16 * (2 * w + c);
      gload16(&lds_b[row0 * 32], gB + (size_t)row0 * K + ko);
    }
    __syncthreads();
    bf16x8 af[4], bfr[2];
#pragma unroll
    for (int m = 0; m < 4; ++m)
      af[m] = *(const bf16x8*)&lds_a[(16 * m + r16) * 32 + g4 * 8];
#pragma unroll
    for (int n = 0; n < 2; ++n)
      bfr[n] = *(const bf16x8*)&lds_b[(32 * w + 16 * n + r16) * 32 + g4 * 8];
#pragma unroll
    for (int m = 0; m < 4; ++m)
#pragma unroll
      for (int n = 0; n < 2; ++n)
        acc[m][n] = __builtin_amdgcn_mfma_f32_16x16x32_bf16(af[m], bfr[n], acc[m][n], 0, 0, 0);
    __syncthreads();
  }

#pragma unroll
  for (int m = 0; m < 4; ++m) {
    const int row = br * 64 + 16 * m + 4 * g4;
#pragma unroll
    for (int n = 0; n < 2; ++n) {
      const int col = bc * 128 + 32 * w + 16 * n + r16;
      const float bvv = bias[col];
#pragma unroll
      for (int r = 0; r < 4; ++r)
        Cp[(size_t)(row + r) * N + col] = acc[m][n][r] + bvv;
    }
  }
}

// ---------------- flash attention (KV-split 2-way, 8-wave blocks) --------------
// 1D grid 1024 (XCD-swizzled), 512 threads (8 waves).  Block = 128 q-rows x one
// key-half (16 of 32 tiles).  Wave (qh,kh): qh=w>>1 (32 q-rows), kh=w&1 (32
// keys/tile).  K + interleaved-V^T staged via gload_lds (dbuf 2x16KB) -- ONE
// staged tile feeds 8 waves.  Max-free softmax; l via ones-row mfma.
// Epilogue exchange padded to 68 f32/row (2-way banks).  T5: setprio(1)
// around the MFMA clusters (QK and PV).

__global__ __launch_bounds__(512)
void k_attn(const bf16* __restrict__ Qg, const bf16* __restrict__ Kg,
            const bf16* __restrict__ Vtg, bf16* __restrict__ PO,
            float* __restrict__ lsum) {
  alignas(16) __shared__ char smem[35328];   // staging 32KB; epilogue 128*68*4+512
  bf16* kbufs = (bf16*)smem;                 // [2][4096]
  bf16* vbufs = (bf16*)(smem + 16384);       // [2][4096]
  const int tid = threadIdx.x, lane = tid & 63, w = tid >> 6;   // w 0..7
  const int bid = blockIdx.x;
  const int swz = (bid & 7) * 128 + (bid >> 3);
  const int half = swz & 1;
  const int id2 = swz >> 1;                       // 0..511
  const int bh = id2 >> 4, q0 = (id2 & 15) * 128;
  const int qh = w >> 1, kh = w & 1;
  const int r16 = lane & 15, g4 = lane >> 4;
  const char* Kb  = (const char*)(Kg  + (size_t)bh * 2048 * 64);
  const char* Vtb = (const char*)(Vtg + (size_t)bh * 64 * 2048);
  const bf16* Qb  = Qg + (size_t)bh * 2048 * 64;

  const int rl = lane >> 3;
  const int colx = ((lane & 7) * 16) ^ (rl << 4);

  bf16x8 qf[2][2];
#pragma unroll
  for (int g = 0; g < 2; ++g) {
    const int qrow = q0 + 32 * qh + 16 * g + r16;
    qf[g][0] = *(const bf16x8*)(Qb + (size_t)qrow * 64 + g4 * 8);
    qf[g][1] = *(const bf16x8*)(Qb + (size_t)qrow * 64 + 32 + g4 * 8);
  }

  f32x4 O[2][4] = {};
  f32x4 O4[2] = {};
  bf16x8 ones8 = {};
  if (r16 == 0)
#pragma unroll
    for (int j = 0; j < 8; ++j) ones8[j] = (bf16)1.f;

  // 8 waves: wave w stages rows 8w..8w+7 (1KB) of each tile
#define STAGE(bufi, t0)                                                          \
  {                                                                              \
    const int row = 8 * w + rl;                                                  \
    gload16(&kbufs[(bufi) * 4096 + w * 512],                                     \
            Kb + (size_t)((t0) + row) * 128 + colx);                             \
    gload16(&vbufs[(bufi) * 4096 + w * 512],                                     \
            Vtb + (size_t)row * 4096 + (size_t)(t0) * 2 + colx);                 \
  }

  const int it0 = half * 16;
  STAGE(0, it0 * 64);
  __syncthreads();

  const int rsw = (r16 & 7) << 4;

#pragma unroll 1
  for (int ii = 0; ii < 16; ++ii) {
    const int bsel = ii & 1;
    if (ii + 1 < 16) STAGE(bsel ^ 1, (it0 + ii + 1) * 64);
    const char* kb = (const char*)kbufs + bsel * 8192 + r16 * 128;
    const char* vb = (const char*)vbufs + bsel * 8192 + r16 * 128;

    // this wave's keys: n = 2*kh + nl, nl = 0,1 (32 keys)
    f32x4 S[2][2];
    __builtin_amdgcn_s_setprio(1);
#pragma unroll
    for (int nl = 0; nl < 2; ++nl) {
      const int n = 2 * kh + nl;
      bf16x8 kf0 = *(const bf16x8*)(kb + n * 2048 + ((g4 * 16) ^ rsw));
      bf16x8 kf1 = *(const bf16x8*)(kb + n * 2048 + ((64 + g4 * 16) ^ rsw));
      f32x4 s = {};
      s = __builtin_amdgcn_mfma_f32_16x16x32_bf16(kf0, qf[0][0], s, 0, 0, 0);
      s = __builtin_amdgcn_mfma_f32_16x16x32_bf16(kf1, qf[0][1], s, 0, 0, 0);
      S[0][nl] = s;
      f32x4 t = {};
      t = __builtin_amdgcn_mfma_f32_16x16x32_bf16(kf0, qf[1][0], t, 0, 0, 0);
      t = __builtin_amdgcn_mfma_f32_16x16x32_bf16(kf1, qf[1][1], t, 0, 0, 0);
      S[1][nl] = t;
    }
    __builtin_amdgcn_s_setprio(0);

    // max-free: P = exp2(S) raw, packed as one K=32 B-fragment per q-group
    bf16x8 pb[2];
#pragma unroll
    for (int g = 0; g < 2; ++g)
#pragma unroll
      for (int nl = 0; nl < 2; ++nl)
#pragma unroll
        for (int r = 0; r < 4; ++r)
          pb[g][nl * 4 + r] = (bf16)exp2f(S[g][nl][r]);

    // O += V^T P^T over this wave's 32 keys (A-frag = interleaved-V b128)
    __builtin_amdgcn_s_setprio(1);
#pragma unroll
    for (int dn = 0; dn < 4; ++dn) {
      bf16x8 vf = *(const bf16x8*)(vb + dn * 2048 + ((32 * g4 + 16 * kh) ^ rsw));
      O[0][dn] = __builtin_amdgcn_mfma_f32_16x16x32_bf16(vf, pb[0], O[0][dn], 0, 0, 0);
      O[1][dn] = __builtin_amdgcn_mfma_f32_16x16x32_bf16(vf, pb[1], O[1][dn], 0, 0, 0);
    }
    O4[0] = __builtin_amdgcn_mfma_f32_16x16x32_bf16(ones8, pb[0], O4[0], 0, 0, 0);
    O4[1] = __builtin_amdgcn_mfma_f32_16x16x32_bf16(ones8, pb[1], O4[1], 0, 0, 0);
    __builtin_amdgcn_s_setprio(0);
    __syncthreads();
  }
#undef STAGE

  // cross-wave kh-combine (plain sums, max-free) via LDS, then store partials.
  // obuf padded to 68 f32/row: r16-lane stride 272B -> 2-way banks (free).
  float* obuf = (float*)smem;                 // [128][68] f32 = 34816 B
  float* lbuf = (float*)(smem + 34816);       // [128]
  if (kh == 1) {
#pragma unroll
    for (int g = 0; g < 2; ++g) {
#pragma unroll
      for (int dn = 0; dn < 4; ++dn)
        *(f32x4*)&obuf[(qh * 32 + g * 16 + r16) * 68 + 16 * dn + 4 * g4] = O[g][dn];
      if (g4 == 0) lbuf[qh * 32 + g * 16 + r16] = O4[g][0];
    }
  }
  __syncthreads();
  if (kh == 0) {
    bf16* POh = PO + (size_t)half * 4194304;
#pragma unroll
    for (int g = 0; g < 2; ++g) {
      const int row = bh * 2048 + q0 + 32 * qh + 16 * g + r16;
      const float ls = __shfl(O4[g][0], r16, 64) + lbuf[qh * 32 + g * 16 + r16];
#pragma unroll
      for (int dn = 0; dn < 4; ++dn) {
        f32x4 os = O[g][dn];
        f32x4 ot = *(const f32x4*)&obuf[(qh * 32 + g * 16 + r16) * 68 + 16 * dn + 4 * g4];
        bf16x4 ov;
#pragma unroll
        for (int r = 0; r < 4; ++r) ov[r] = (bf16)(os[r] + ot[r]);
        *(bf16x4*)(POh + (size_t)row * 64 + 16 * dn + 4 * g4) = ov;
      }
      if (g4 == 0) lsum[half * 65536 + row] = ls;
    }
  }
}

// ---------------- combine: O = (O0 + O1) / (l0 + l1) ----------------

__global__ __launch_bounds__(256)
void k_combine(const bf16* __restrict__ PO, const float* __restrict__ lsum,
               bf16* __restrict__ attnb) {
  const int idx = blockIdx.x * 256 + threadIdx.x;   // 524288 = 65536 rows x 8 segs
  const int row = idx >> 3, seg = idx & 7;
  const float inv = 1.f / (lsum[row] + lsum[65536 + row]);
  bf16x8 p0 = *(const bf16x8*)(PO + (size_t)row * 64 + seg * 8);
  bf16x8 p1 = *(const bf16x8*)(PO + 4194304 + (size_t)row * 64 + seg * 8);
  bf16x8 o;
#pragma unroll
  for (int j = 0; j < 8; ++j)
    o[j] = (bf16)(((float)p0[j] + (float)p1[j]) * inv);
  const int bh = row >> 11, t = row & 2047;
  const int b = bh >> 4, h = bh & 15;
  *(bf16x8*)(attnb + ((size_t)(b * 2048 + t)) * 1024 + h * 64 + seg * 8) = o;
}

// ---------------- launch ----------------

extern "C" void kernel_launch(void* const* d_in, const int* in_sizes, int n_in,
                              void* d_out, int out_size, void* d_ws, size_t ws_size,
                              hipStream_t stream) {
  const float* x     = (const float*)d_in[0];
  const float* w_qkv = (const float*)d_in[1];
  const float* b_qkv = (const float*)d_in[2];
  const float* w_out = (const float*)d_in[3];
  const float* b_out = (const float*)d_in[4];
  float* out = (float*)d_out;

  char* ws = (char*)d_ws;
  bf16* xb    = (bf16*)(ws);                 // reused as PO after qkv
  bf16* wqkvT = (bf16*)(ws + 8388608);
  bf16* Qb    = (bf16*)(ws + 16777216);
  bf16* Kb    = (bf16*)(ws + 25165824);
  bf16* Vtb   = (bf16*)(ws + 33554432);
  bf16* attnb = (bf16*)(ws + 41943040);
  bf16* woutT = (bf16*)(ws + 50331648);
  float* lsum = (float*)(ws + 52428800);
  bf16* PO    = (bf16*)(ws);                 // [2][65536][64] over xb+wqkvT

  k_convert_x<<<4096 * 1024 / 4 / 256, 256, 0, stream>>>(x, xb, 4096 * 1024);
  k_transpose_bf16<<<dim3(3072 / 32, 1024 / 32), dim3(32, 8), 0, stream>>>(w_qkv, wqkvT, 1024, 3072);
  k_transpose_bf16<<<dim3(1024 / 32, 1024 / 32), dim3(32, 8), 0, stream>>>(w_out, woutT, 1024, 1024);
  k_gemm_qkv<<<32 * 24, 256, 0, stream>>>(xb, wqkvT, b_qkv, Qb, Kb, Vtb);
  k_attn<<<1024, 512, 0, stream>>>(Qb, Kb, Vtb, PO, lsum);
  k_combine<<<2048, 256, 0, stream>>>(PO, lsum, attnb);
  k_gemm_out<<<512, 256, 0, stream>>>(attnb, woutT, b_out, out, 4096, 1024, 1024);
}

// Round 25
// 128.124 us; speedup vs baseline: 1.0030x; 1.0001x over previous
//
#include <hip/hip_runtime.h>
#include <hip/hip_bf16.h>
#include <stdint.h>

// Problem: B=2, T=2048, D=1024, H=16, hd=64.  M = B*T = 4096.
// Pipeline: x->bf16 ; w^T->bf16 ; QKV gemm w/ fused bias+RoPE+head-split ;
// flash attn (KV-split 2-way, 8-wave blocks, MAX-FREE softmax) ; combine ;
// out gemm (64x128 tiles, 2 blocks/CU).
// Workspace layout (bytes), < 64 MiB (R2 post-mortem):
//   0        x_bf16 [4096][1024]      -- later reused as partialO [2][65536][64] bf16
//   8388608  wqkvT  [3072][1024]      -- (PO spans [0, 16777216))
//   16777216 Q      [32][2048][64]    (pre-scaled by log2e/8, RoPE'd)
//   25165824 K      [32][2048][64]    (RoPE'd)
//   33554432 V^T    [32][64][2048]    (transposed; key dim INTERLEAVED per
//                                      64-block: pos(16a+4g+r)=16g+8(a>>1)+4(a&1)+r)
//   41943040 attn   [4096][1024]
//   50331648 woutT  [1024][1024]
//   52428800 l      [2][65536] float
// Max-free softmax: bf16-input scores are bounded << 2^120 in log2 domain, so
// P=exp2(S) raw cannot overflow and the reference-max cancels exactly in O/l.
// R15 (x2 w/ R10): V direct-from-L2 loses to LDS-staged V.
// R18: fusing combine into out-gemm regressed.  R19: qkv 64x128 retile
// regressed.  R21: qkv BK=64 neutral.  R22: padded epilogue exchange (68
// f32/row) -- conflicts 4.85M->2.23M, attn -2us (prediction matched).
// R23: T5 s_setprio(1) around attn MFMA clusters (m191: +4-7% attn; attn only,
// NOT the gemms per m190).

typedef __bf16 bf16;
typedef __bf16 bf16x8 __attribute__((ext_vector_type(8)));
typedef __bf16 bf16x4 __attribute__((ext_vector_type(4)));
typedef float  f32x4  __attribute__((ext_vector_type(4)));

__device__ __forceinline__ void gload16(void* lds, const void* g) {
  __builtin_amdgcn_global_load_lds((__attribute__((address_space(1))) void*)(void*)g,
                                   (__attribute__((address_space(3))) void*)lds, 16, 0, 0);
}

// ---------------- conversion kernels ----------------

__global__ void k_convert_x(const float* __restrict__ x, bf16* __restrict__ xb, int n) {
  int i = (blockIdx.x * blockDim.x + threadIdx.x) * 4;
  if (i >= n) return;
  float4 v = *(const float4*)(x + i);
  bf16x4 o;
  o.x = (bf16)v.x; o.y = (bf16)v.y; o.z = (bf16)v.z; o.w = (bf16)v.w;
  *(bf16x4*)(xb + i) = o;
}

__global__ void k_transpose_bf16(const float* __restrict__ in, bf16* __restrict__ out,
                                 int rows, int cols) {
  __shared__ float t[32][33];
  int c0 = blockIdx.x * 32, r0 = blockIdx.y * 32;
  for (int i = threadIdx.y; i < 32; i += 8)
    t[i][threadIdx.x] = in[(size_t)(r0 + i) * cols + c0 + threadIdx.x];
  __syncthreads();
  for (int i = threadIdx.y; i < 32; i += 8)
    out[(size_t)(c0 + i) * rows + r0 + threadIdx.x] = (bf16)t[threadIdx.x][i];
}

// ---------------- QKV GEMM with fused bias + RoPE + head split ----------------
// RoPE trig via native v_sin/v_cos (input in revolutions, fract-reduced).

__global__ __launch_bounds__(256)
void k_gemm_qkv(const bf16* __restrict__ A, const bf16* __restrict__ Bt,
                const float* __restrict__ bias, bf16* __restrict__ Qd,
                bf16* __restrict__ Kd, bf16* __restrict__ Vtd) {
  alignas(16) __shared__ bf16 lds_a[128 * 32];
  alignas(16) __shared__ bf16 lds_b[128 * 32];
  const int tid = threadIdx.x;
  const int lane = tid & 63, w = tid >> 6;
  const int wr = w >> 1, wc = w & 1;
  const int bid = blockIdx.x;
  const int swz = (bid & 7) * 96 + (bid >> 3);
  const int br = swz / 24, bc = swz % 24;
  const int r16 = lane & 15, g4 = lane >> 4;

  f32x4 acc[4][4] = {};
  const bf16* gA = A + (size_t)(br * 128 + (lane >> 2)) * 1024 + (lane & 3) * 8;
  const bf16* gB = Bt + (size_t)(bc * 128 + (lane >> 2)) * 1024 + (lane & 3) * 8;

  for (int kt = 0; kt < 32; ++kt) {
    const int ko = kt * 32;
#pragma unroll
    for (int it = 0; it < 2; ++it) {
      const int row0 = 16 * (4 * it + w);
      gload16(&lds_a[row0 * 32], gA + (size_t)row0 * 1024 + ko);
      gload16(&lds_b[row0 * 32], gB + (size_t)row0 * 1024 + ko);
    }
    __syncthreads();
    bf16x8 af[4], bfr[4];
#pragma unroll
    for (int m = 0; m < 4; ++m)
      af[m] = *(const bf16x8*)&lds_a[(wr * 64 + 16 * m + r16) * 32 + g4 * 8];
#pragma unroll
    for (int n = 0; n < 4; ++n)
      bfr[n] = *(const bf16x8*)&lds_b[(wc * 64 + 16 * n + r16) * 32 + g4 * 8];
#pragma unroll
    for (int m = 0; m < 4; ++m)
#pragma unroll
      for (int n = 0; n < 4; ++n)
        acc[m][n] = __builtin_amdgcn_mfma_f32_16x16x32_bf16(af[m], bfr[n], acc[m][n], 0, 0, 0);
    __syncthreads();
  }

  const int reg = bc >> 3;                       // 0=Q, 1=K, 2=V
  const int h = ((bc & 7) << 1) | wc;            // head 0..15
  const float bq = 0.125f * 1.4426950408889634f; // (1/sqrt(64)) * log2(e)
  const float Lc = 13.287712379549449f / 32.0f;  // log2(10000)/32
  const float inv2pi = 0.15915494309189535f;
  const float if0r = exp2f(-(float)r16 * Lc) * inv2pi;        // rev per t
  const float if1r = exp2f(-(float)(16 + r16) * Lc) * inv2pi;
  float bv[4];
#pragma unroll
  for (int n = 0; n < 4; ++n) bv[n] = bias[bc * 128 + wc * 64 + 16 * n + r16];

  if (reg == 2) {
    // V: V^T[b*16+h][d][t'], key pos interleaved within each 64-block:
    // t = 64blk+16a+4g+r -> t' = 64blk+16g+8(a>>1)+4(a&1)+r
#pragma unroll
    for (int m = 0; m < 4; ++m) {
      const int row0 = br * 128 + wr * 64 + 16 * m + 4 * g4;
      const int t0 = row0 & 2047, b = row0 >> 11;
      const int pos = (t0 & ~63) | (((t0 >> 2) & 3) << 4) | (((t0 >> 5) & 1) << 3) |
                      (((t0 >> 4) & 1) << 2);
#pragma unroll
      for (int n = 0; n < 4; ++n) {
        bf16x4 pk;
#pragma unroll
        for (int r = 0; r < 4; ++r) pk[r] = (bf16)(acc[m][n][r] + bv[n]);
        *(bf16x4*)(Vtd + ((size_t)((b * 16 + h) * 64) + 16 * n + r16) * 2048 + pos) = pk;
      }
    }
  } else {
    bf16* dst = (reg == 0) ? Qd : Kd;
#pragma unroll
    for (int m = 0; m < 4; ++m) {
#pragma unroll
      for (int r = 0; r < 4; ++r) {
        const int row = br * 128 + wr * 64 + 16 * m + 4 * g4 + r;
        const int t = row & 2047, b = row >> 11;
        bf16* o = dst + ((size_t)(b * 16 + h) * 2048 + t) * 64;
        const float v0 = acc[m][0][r] + bv[0];
        const float v1 = acc[m][1][r] + bv[1];
        const float v2 = acc[m][2][r] + bv[2];
        const float v3 = acc[m][3][r] + bv[3];
        const float tf = (float)t;
        float rv0 = tf * if0r; rv0 -= floorf(rv0);
        float rv1 = tf * if1r; rv1 -= floorf(rv1);
        const float s0 = __builtin_amdgcn_sinf(rv0), c0 = __builtin_amdgcn_cosf(rv0);
        const float s1 = __builtin_amdgcn_sinf(rv1), c1 = __builtin_amdgcn_cosf(rv1);
        float r0 = v0 * c0 - v2 * s0, r2 = v0 * s0 + v2 * c0;
        float r1 = v1 * c1 - v3 * s1, r3 = v1 * s1 + v3 * c1;
        if (reg == 0) { r0 *= bq; r1 *= bq; r2 *= bq; r3 *= bq; }
        o[r16]      = (bf16)r0;
        o[16 + r16] = (bf16)r1;
        o[32 + r16] = (bf16)r2;
        o[48 + r16] = (bf16)r3;
      }
    }
  }
}

// ---------------- out GEMM (64x128 tiles, grid 512 = 2 blocks/CU) ----------------
// Wave w owns the 64x32 column strip cols [32w, 32w+32).

__global__ __launch_bounds__(256)
void k_gemm_out(const bf16* __restrict__ A, const bf16* __restrict__ Bt,
                const float* __restrict__ bias, float* __restrict__ Cp,
                int M, int N, int K) {
  alignas(16) __shared__ bf16 lds_a[64 * 32];
  alignas(16) __shared__ bf16 lds_b[128 * 32];
  const int tid = threadIdx.x;
  const int lane = tid & 63, w = tid >> 6;
  const int nb = N >> 7;
  const int nwg = gridDim.x;
  const int bid = blockIdx.x;
  const int swz = (bid & 7) * (nwg >> 3) + (bid >> 3);
  const int br = swz / nb, bc = swz % nb;
  const int r16 = lane & 15, g4 = lane >> 4;

  f32x4 acc[4][2] = {};
  const int nk = K >> 5;
  const bf16* gA = A + (size_t)(br * 64 + 16 * w + (lane >> 2)) * K + (lane & 3) * 8;
  const bf16* gB = Bt + (size_t)(bc * 128 + (lane >> 2)) * K + (lane & 3) * 8;

  for (int kt = 0; kt < nk; ++kt) {
    const int ko = kt * 32;
    gload16(&lds_a[w * 512], gA + ko);
#pragma unroll
    for (int c = 0; c < 2; ++c) {
      const int row0 = 16 * (2 * w + c);
      gload16(&lds_b[row0 * 32], gB + (size_t)row0 * K + ko);
    }
    __syncthreads();
    bf16x8 af[4], bfr[2];
#pragma unroll
    for (int m = 0; m < 4; ++m)
      af[m] = *(const bf16x8*)&lds_a[(16 * m + r16) * 32 + g4 * 8];
#pragma unroll
    for (int n = 0; n < 2; ++n)
      bfr[n] = *(const bf16x8*)&lds_b[(32 * w + 16 * n + r16) * 32 + g4 * 8];
#pragma unroll
    for (int m = 0; m < 4; ++m)
#pragma unroll
      for (int n = 0; n < 2; ++n)
        acc[m][n] = __builtin_amdgcn_mfma_f32_16x16x32_bf16(af[m], bfr[n], acc[m][n], 0, 0, 0);
    __syncthreads();
  }

#pragma unroll
  for (int m = 0; m < 4; ++m) {
    const int row = br * 64 + 16 * m + 4 * g4;
#pragma unroll
    for (int n = 0; n < 2; ++n) {
      const int col = bc * 128 + 32 * w + 16 * n + r16;
      const float bvv = bias[col];
#pragma unroll
      for (int r = 0; r < 4; ++r)
        Cp[(size_t)(row + r) * N + col] = acc[m][n][r] + bvv;
    }
  }
}

// ---------------- flash attention (KV-split 2-way, 8-wave blocks) --------------
// 1D grid 1024 (XCD-swizzled), 512 threads (8 waves).  Block = 128 q-rows x one
// key-half (16 of 32 tiles).  Wave (qh,kh): qh=w>>1 (32 q-rows), kh=w&1 (32
// keys/tile).  K + interleaved-V^T staged via gload_lds (dbuf 2x16KB) -- ONE
// staged tile feeds 8 waves.  Max-free softmax; l via ones-row mfma.
// Epilogue exchange padded to 68 f32/row (2-way banks).  T5: setprio(1)
// around the MFMA clusters (QK and PV).

__global__ __launch_bounds__(512)
void k_attn(const bf16* __restrict__ Qg, const bf16* __restrict__ Kg,
            const bf16* __restrict__ Vtg, bf16* __restrict__ PO,
            float* __restrict__ lsum) {
  alignas(16) __shared__ char smem[35328];   // staging 32KB; epilogue 128*68*4+512
  bf16* kbufs = (bf16*)smem;                 // [2][4096]
  bf16* vbufs = (bf16*)(smem + 16384);       // [2][4096]
  const int tid = threadIdx.x, lane = tid & 63, w = tid >> 6;   // w 0..7
  const int bid = blockIdx.x;
  const int swz = (bid & 7) * 128 + (bid >> 3);
  const int half = swz & 1;
  const int id2 = swz >> 1;                       // 0..511
  const int bh = id2 >> 4, q0 = (id2 & 15) * 128;
  const int qh = w >> 1, kh = w & 1;
  const int r16 = lane & 15, g4 = lane >> 4;
  const char* Kb  = (const char*)(Kg  + (size_t)bh * 2048 * 64);
  const char* Vtb = (const char*)(Vtg + (size_t)bh * 64 * 2048);
  const bf16* Qb  = Qg + (size_t)bh * 2048 * 64;

  const int rl = lane >> 3;
  const int colx = ((lane & 7) * 16) ^ (rl << 4);

  bf16x8 qf[2][2];
#pragma unroll
  for (int g = 0; g < 2; ++g) {
    const int qrow = q0 + 32 * qh + 16 * g + r16;
    qf[g][0] = *(const bf16x8*)(Qb + (size_t)qrow * 64 + g4 * 8);
    qf[g][1] = *(const bf16x8*)(Qb + (size_t)qrow * 64 + 32 + g4 * 8);
  }

  f32x4 O[2][4] = {};
  f32x4 O4[2] = {};
  bf16x8 ones8 = {};
  if (r16 == 0)
#pragma unroll
    for (int j = 0; j < 8; ++j) ones8[j] = (bf16)1.f;

  // 8 waves: wave w stages rows 8w..8w+7 (1KB) of each tile
#define STAGE(bufi, t0)                                                          \
  {                                                                              \
    const int row = 8 * w + rl;                                                  \
    gload16(&kbufs[(bufi) * 4096 + w * 512],                                     \
            Kb + (size_t)((t0) + row) * 128 + colx);                             \
    gload16(&vbufs[(bufi) * 4096 + w * 512],                                     \
            Vtb + (size_t)row * 4096 + (size_t)(t0) * 2 + colx);                 \
  }

  const int it0 = half * 16;
  STAGE(0, it0 * 64);
  __syncthreads();

  const int rsw = (r16 & 7) << 4;

#pragma unroll 1
  for (int ii = 0; ii < 16; ++ii) {
    const int bsel = ii & 1;
    if (ii + 1 < 16) STAGE(bsel ^ 1, (it0 + ii + 1) * 64);
    const char* kb = (const char*)kbufs + bsel * 8192 + r16 * 128;
    const char* vb = (const char*)vbufs + bsel * 8192 + r16 * 128;

    // this wave's keys: n = 2*kh + nl, nl = 0,1 (32 keys)
    f32x4 S[2][2];
    __builtin_amdgcn_s_setprio(1);
#pragma unroll
    for (int nl = 0; nl < 2; ++nl) {
      const int n = 2 * kh + nl;
      bf16x8 kf0 = *(const bf16x8*)(kb + n * 2048 + ((g4 * 16) ^ rsw));
      bf16x8 kf1 = *(const bf16x8*)(kb + n * 2048 + ((64 + g4 * 16) ^ rsw));
      f32x4 s = {};
      s = __builtin_amdgcn_mfma_f32_16x16x32_bf16(kf0, qf[0][0], s, 0, 0, 0);
      s = __builtin_amdgcn_mfma_f32_16x16x32_bf16(kf1, qf[0][1], s, 0, 0, 0);
      S[0][nl] = s;
      f32x4 t = {};
      t = __builtin_amdgcn_mfma_f32_16x16x32_bf16(kf0, qf[1][0], t, 0, 0, 0);
      t = __builtin_amdgcn_mfma_f32_16x16x32_bf16(kf1, qf[1][1], t, 0, 0, 0);
      S[1][nl] = t;
    }
    __builtin_amdgcn_s_setprio(0);

    // max-free: P = exp2(S) raw, packed as one K=32 B-fragment per q-group
    bf16x8 pb[2];
#pragma unroll
    for (int g = 0; g < 2; ++g)
#pragma unroll
      for (int nl = 0; nl < 2; ++nl)
#pragma unroll
        for (int r = 0; r < 4; ++r)
          pb[g][nl * 4 + r] = (bf16)exp2f(S[g][nl][r]);

    // O += V^T P^T over this wave's 32 keys (A-frag = interleaved-V b128)
    __builtin_amdgcn_s_setprio(1);
#pragma unroll
    for (int dn = 0; dn < 4; ++dn) {
      bf16x8 vf = *(const bf16x8*)(vb + dn * 2048 + ((32 * g4 + 16 * kh) ^ rsw));
      O[0][dn] = __builtin_amdgcn_mfma_f32_16x16x32_bf16(vf, pb[0], O[0][dn], 0, 0, 0);
      O[1][dn] = __builtin_amdgcn_mfma_f32_16x16x32_bf16(vf, pb[1], O[1][dn], 0, 0, 0);
    }
    O4[0] = __builtin_amdgcn_mfma_f32_16x16x32_bf16(ones8, pb[0], O4[0], 0, 0, 0);
    O4[1] = __builtin_amdgcn_mfma_f32_16x16x32_bf16(ones8, pb[1], O4[1], 0, 0, 0);
    __builtin_amdgcn_s_setprio(0);
    __syncthreads();
  }
#undef STAGE

  // cross-wave kh-combine (plain sums, max-free) via LDS, then store partials.
  // obuf padded to 68 f32/row: r16-lane stride 272B -> 2-way banks (free).
  float* obuf = (float*)smem;                 // [128][68] f32 = 34816 B
  float* lbuf = (float*)(smem + 34816);       // [128]
  if (kh == 1) {
#pragma unroll
    for (int g = 0; g < 2; ++g) {
#pragma unroll
      for (int dn = 0; dn < 4; ++dn)
        *(f32x4*)&obuf[(qh * 32 + g * 16 + r16) * 68 + 16 * dn + 4 * g4] = O[g][dn];
      if (g4 == 0) lbuf[qh * 32 + g * 16 + r16] = O4[g][0];
    }
  }
  __syncthreads();
  if (kh == 0) {
    bf16* POh = PO + (size_t)half * 4194304;
#pragma unroll
    for (int g = 0; g < 2; ++g) {
      const int row = bh * 2048 + q0 + 32 * qh + 16 * g + r16;
      const float ls = __shfl(O4[g][0], r16, 64) + lbuf[qh * 32 + g * 16 + r16];
#pragma unroll
      for (int dn = 0; dn < 4; ++dn) {
        f32x4 os = O[g][dn];
        f32x4 ot = *(const f32x4*)&obuf[(qh * 32 + g * 16 + r16) * 68 + 16 * dn + 4 * g4];
        bf16x4 ov;
#pragma unroll
        for (int r = 0; r < 4; ++r) ov[r] = (bf16)(os[r] + ot[r]);
        *(bf16x4*)(POh + (size_t)row * 64 + 16 * dn + 4 * g4) = ov;
      }
      if (g4 == 0) lsum[half * 65536 + row] = ls;
    }
  }
}

// ---------------- combine: O = (O0 + O1) / (l0 + l1) ----------------

__global__ __launch_bounds__(256)
void k_combine(const bf16* __restrict__ PO, const float* __restrict__ lsum,
               bf16* __restrict__ attnb) {
  const int idx = blockIdx.x * 256 + threadIdx.x;   // 524288 = 65536 rows x 8 segs
  const int row = idx >> 3, seg = idx & 7;
  const float inv = 1.f / (lsum[row] + lsum[65536 + row]);
  bf16x8 p0 = *(const bf16x8*)(PO + (size_t)row * 64 + seg * 8);
  bf16x8 p1 = *(const bf16x8*)(PO + 4194304 + (size_t)row * 64 + seg * 8);
  bf16x8 o;
#pragma unroll
  for (int j = 0; j < 8; ++j)
    o[j] = (bf16)(((float)p0[j] + (float)p1[j]) * inv);
  const int bh = row >> 11, t = row & 2047;
  const int b = bh >> 4, h = bh & 15;
  *(bf16x8*)(attnb + ((size_t)(b * 2048 + t)) * 1024 + h * 64 + seg * 8) = o;
}

// ---------------- launch ----------------

extern "C" void kernel_launch(void* const* d_in, const int* in_sizes, int n_in,
                              void* d_out, int out_size, void* d_ws, size_t ws_size,
                              hipStream_t stream) {
  const float* x     = (const float*)d_in[0];
  const float* w_qkv = (const float*)d_in[1];
  const float* b_qkv = (const float*)d_in[2];
  const float* w_out = (const float*)d_in[3];
  const float* b_out = (const float*)d_in[4];
  float* out = (float*)d_out;

  char* ws = (char*)d_ws;
  bf16* xb    = (bf16*)(ws);                 // reused as PO after qkv
  bf16* wqkvT = (bf16*)(ws + 8388608);
  bf16* Qb    = (bf16*)(ws + 16777216);
  bf16* Kb    = (bf16*)(ws + 25165824);
  bf16* Vtb   = (bf16*)(ws + 33554432);
  bf16* attnb = (bf16*)(ws + 41943040);
  bf16* woutT = (bf16*)(ws + 50331648);
  float* lsum = (float*)(ws + 52428800);
  bf16* PO    = (bf16*)(ws);                 // [2][65536][64] over xb+wqkvT

  k_convert_x<<<4096 * 1024 / 4 / 256, 256, 0, stream>>>(x, xb, 4096 * 1024);
  k_transpose_bf16<<<dim3(3072 / 32, 1024 / 32), dim3(32, 8), 0, stream>>>(w_qkv, wqkvT, 1024, 3072);
  k_transpose_bf16<<<dim3(1024 / 32, 1024 / 32), dim3(32, 8), 0, stream>>>(w_out, woutT, 1024, 1024);
  k_gemm_qkv<<<32 * 24, 256, 0, stream>>>(xb, wqkvT, b_qkv, Qb, Kb, Vtb);
  k_attn<<<1024, 512, 0, stream>>>(Qb, Kb, Vtb, PO, lsum);
  k_combine<<<2048, 256, 0, stream>>>(PO, lsum, attnb);
  k_gemm_out<<<512, 256, 0, stream>>>(attnb, woutT, b_out, out, 4096, 1024, 1024);
}